// Round 3
// baseline (1615.743 us; speedup 1.0000x reference)
//
#include <hip/hip_runtime.h>

typedef _Float16 half8 __attribute__((ext_vector_type(8)));
typedef float f32x4 __attribute__((ext_vector_type(4)));

#define NT 512   // timesteps
#define NB 128   // batch
#define NI 256   // input dim
#define NH 512   // hidden dim
#define FLAG_STRIDE 16  // ints -> 64B per flag, avoid line sharing

// ---------------------------------------------------------------------------
// W (fp32 [N][K]) -> fragment-linear f16 for MFMA B-operand.
// Block b = t_n*KT + t_k; lane l holds 8 elems: n = t_n*16 + (l&15),
// k = t_k*32 + (l>>4)*8 + j. Also zeroes the flags (ws is re-poisoned each
// launch). Grid 196*256 = 50176 >= 32768 + 16384 + 256.
// ---------------------------------------------------------------------------
__global__ void w_transform(const float* __restrict__ Whh,
                            const float* __restrict__ Win,
                            _Float16* __restrict__ Wf_hh,
                            _Float16* __restrict__ Wf_in,
                            int* __restrict__ flags) {
  int tid = blockIdx.x * blockDim.x + threadIdx.x;
  if (tid < 32768) {                    // W_hh: 32 n-tiles * 16 k-tiles
    int l = tid & 63, b = tid >> 6;
    int tk = b & 15, tn = b >> 4;
    int n = tn * 16 + (l & 15);
    int k = tk * 32 + (l >> 4) * 8;
    const float* src = Whh + (size_t)n * NH + k;
    _Float16* dst = Wf_hh + (size_t)tid * 8;
#pragma unroll
    for (int j = 0; j < 8; ++j) dst[j] = (_Float16)src[j];
  } else if (tid < 32768 + 16384) {     // W_in: 32 n-tiles * 8 k-tiles
    int t2 = tid - 32768;
    int l = t2 & 63, b = t2 >> 6;
    int tk = b & 7, tn = b >> 3;
    int n = tn * 16 + (l & 15);
    int k = tk * 32 + (l >> 4) * 8;
    const float* src = Win + (size_t)n * NI + k;
    _Float16* dst = Wf_in + (size_t)t2 * 8;
#pragma unroll
    for (int j = 0; j < 8; ++j) dst[j] = (_Float16)src[j];
  } else if (tid < 32768 + 16384 + 256) {
    flags[tid - 32768 - 16384] = 0;
  }
}

// ---------------------------------------------------------------------------
// Phase 1: xin = x @ W_in^T  (M=65536, K=256, N=512), fp32 out into d_out.
// (unchanged from the passing baseline)
// ---------------------------------------------------------------------------
__global__ __launch_bounds__(256)
void input_proj(const float* __restrict__ x,
                const _Float16* __restrict__ Wf_in,
                float* __restrict__ xin) {
  int lane = threadIdx.x & 63;
  int wv = threadIdx.x >> 6;
  int m0 = blockIdx.x * 16;
  int c = lane & 15, q = lane >> 4;
  int row = m0 + c;

  f32x4 acc[8];
#pragma unroll
  for (int i = 0; i < 8; ++i) acc[i] = (f32x4){0.f, 0.f, 0.f, 0.f};

#pragma unroll
  for (int kc = 0; kc < 8; ++kc) {
    const float4* ap = (const float4*)(x + (size_t)row * NI + kc * 32 + q * 8);
    float4 a0 = ap[0], a1 = ap[1];
    half8 a;
    a[0] = (_Float16)a0.x; a[1] = (_Float16)a0.y;
    a[2] = (_Float16)a0.z; a[3] = (_Float16)a0.w;
    a[4] = (_Float16)a1.x; a[5] = (_Float16)a1.y;
    a[6] = (_Float16)a1.z; a[7] = (_Float16)a1.w;
#pragma unroll
    for (int nt = 0; nt < 8; ++nt) {
      int tn = wv * 8 + nt;
      const half8* bp =
          (const half8*)(Wf_in + (((size_t)(tn * 8 + kc)) * 64 + lane) * 8);
      acc[nt] = __builtin_amdgcn_mfma_f32_16x16x32_f16(a, *bp, acc[nt], 0, 0, 0);
    }
  }
#pragma unroll
  for (int nt = 0; nt < 8; ++nt) {
    int n = wv * 128 + nt * 16 + c;
#pragma unroll
    for (int r = 0; r < 4; ++r) {
      int m = q * 4 + r;
      xin[(size_t)(m0 + m) * NH + n] = acc[nt][r];
    }
  }
}

// ---------------------------------------------------------------------------
// Phase 2: recurrence. 16 wgs = 8 batch-groups x 2 col-slices (256 cols each).
// 512 threads = 8 waves; each wave owns 2 n-tiles (32 cols), all 16 k-chunks
// of W_hh resident in VGPRs (128 VGPRs/lane of B-fragments).
//
// Protocol = the PROVEN baseline flag scheme, unchanged semantics:
//  * hbuf f16, col-major [2][NH][NB] (aliases Wf_in; never needs zeroing —
//    flags gate every read, and each slot is fully written before its flag).
//  * publisher: epilogue stores h (f16) into slot t&1 via relaxed agent
//    atomics; __syncthreads() (compiler drains vmcnt(0) -> LLC-visible);
//    tid0 stores flag := t+1 (relaxed agent).
//  * consumer at step t: spin partner flag >= t, then load slot (t-1)&1.
//    Issue-order load-after-observed-flag + publisher drain = data valid.
//  * slot reuse safe: partner rewrites slot (t-1)&1 only at its step t+1,
//    after observing our flag t+1, stored after our step-t reads completed.
// Latency hiding: own 256 k-cols (our own published half, fresh in LDS) are
// consumed by MFMAs BEFORE the spin, covering the partner's lag + LLC RT.
// Exactly 2 __syncthreads per step, no inline asm, no manual waitcnt.
// ---------------------------------------------------------------------------
__global__ __launch_bounds__(512, 2)
void recurrence(float* __restrict__ dout,          // xin in-place -> h, + final
                const float* __restrict__ h0,
                const _Float16* __restrict__ Wf,   // fragment-linear W_hh
                unsigned long long* __restrict__ hbuf64,  // [2][NH][NB] f16
                int* __restrict__ flags) {
  __shared__ _Float16 h_sh[16][520];   // full h rows (A source), 16B rows

  int g = blockIdx.x >> 1, s = blockIdx.x & 1;
  int tid = threadIdx.x, lane = tid & 63, wv = tid >> 6;  // 8 waves
  int c = lane & 15, q = lane >> 4;
  int m0 = g * 16;            // batch row base
  int sc = s * 256;           // own hidden-col base (also own k-range)
  int P0 = 256 - sc;          // partner col base

  // resident B-fragments: this wave's 2 n-tiles (32 cols), all 16 k-chunks,
  // own-k-first ordering so both MFMA loops use compile-time indices.
  int ntg = s * 16 + wv * 2;
  half8 bfrag[2][16];
#pragma unroll
  for (int nt = 0; nt < 2; ++nt) {
#pragma unroll
    for (int kk = 0; kk < 16; ++kk) {
      int kcg = (kk < 8) ? (s * 8 + kk) : ((8 - s * 8) + (kk - 8));
      bfrag[nt][kk] =
          *(const half8*)(Wf + (((size_t)(ntg + nt) * 16 + kcg) * 64 + lane) * 8);
    }
  }

  // fp32 master state: 2 n-tiles x 4 rows per thread (C-fragment layout)
  float h32r[2][4];
#pragma unroll
  for (int nt = 0; nt < 2; ++nt)
#pragma unroll
    for (int r = 0; r < 4; ++r)
      h32r[nt][r] =
          h0[(size_t)(m0 + q * 4 + r) * NH + sc + wv * 32 + nt * 16 + c];

  // init h_sh (both halves) from h0
  for (int i = tid; i < 16 * 512; i += 512)
    h_sh[i >> 9][i & 511] = (_Float16)h0[(size_t)(m0 + (i >> 9)) * NH + (i & 511)];
  __syncthreads();

  unsigned short* hsb = (unsigned short*)&h_sh[0][0];
  int* fbase = flags + g * 2 * FLAG_STRIDE;
  int* myflag = fbase + s * FLAG_STRIDE;
  int* pflag  = fbase + (1 - s) * FLAG_STRIDE;

#pragma unroll 1
  for (int t = 0; t < NT; ++t) {
    // xin: 8 scattered dwords, consumed in the epilogue (latency hidden)
    const float* xp = dout + ((size_t)t * NB + m0) * NH + sc;
    float xv[2][4];
#pragma unroll
    for (int nt = 0; nt < 2; ++nt)
#pragma unroll
      for (int r = 0; r < 4; ++r)
        xv[nt][r] = xp[(size_t)(q * 4 + r) * NH + wv * 32 + nt * 16 + c];

    // --- own-half MFMAs: k in our own 256 cols (h_sh own half is fresh) ---
    f32x4 acc[2][2];
#pragma unroll
    for (int nt = 0; nt < 2; ++nt) {
      acc[nt][0] = (f32x4){0.f, 0.f, 0.f, 0.f};
      acc[nt][1] = (f32x4){0.f, 0.f, 0.f, 0.f};
    }
#pragma unroll
    for (int kk = 0; kk < 8; ++kk) {
      int kcg = s * 8 + kk;
      half8 a = *(const half8*)&h_sh[c][kcg * 32 + q * 8];
#pragma unroll
      for (int nt = 0; nt < 2; ++nt)
        acc[nt][kk & 1] = __builtin_amdgcn_mfma_f32_16x16x32_f16(
            a, bfrag[nt][kk], acc[nt][kk & 1], 0, 0, 0);
    }

    if (t > 0) {
      // --- spin on partner's publish of step t-1 (value t) ---
      while (__hip_atomic_load(pflag, __ATOMIC_RELAXED,
                               __HIP_MEMORY_SCOPE_AGENT) < t) {
      }
      // --- refill remote half of h_sh: 1024 u64 chunks, 2 per thread ---
      const unsigned long long* pb =
          hbuf64 + ((size_t)((t - 1) & 1) * NH + P0) * 32 + (m0 >> 2);
#pragma unroll
      for (int j = 0; j < 2; ++j) {
        int k = tid + j * 512;          // [0,1024): col=k>>2, row-quad=k&3
        int col = k >> 2, rq = k & 3;
        unsigned long long v = __hip_atomic_load(
            pb + (size_t)col * 32 + rq, __ATOMIC_RELAXED,
            __HIP_MEMORY_SCOPE_AGENT);
#pragma unroll
        for (int i = 0; i < 4; ++i)
          hsb[(size_t)(rq * 4 + i) * 520 + P0 + col] =
              (unsigned short)(v >> (16 * i));
      }
    }
    __syncthreads();  // (1) remote half ready; own-half reads all done

    // --- remote-half MFMAs ---
#pragma unroll
    for (int kk = 8; kk < 16; ++kk) {
      int kcg = (8 - s * 8) + (kk - 8);
      half8 a = *(const half8*)&h_sh[c][kcg * 32 + q * 8];
#pragma unroll
      for (int nt = 0; nt < 2; ++nt)
        acc[nt][kk & 1] = __builtin_amdgcn_mfma_f32_16x16x32_f16(
            a, bfrag[nt][kk], acc[nt][kk & 1], 0, 0, 0);
    }

    // --- epilogue: h_new = relu(0.8 h + 0.2 (xin + P)) ---
    bool last = (t == NT - 1);
    int slotw = t & 1;
#pragma unroll
    for (int nt = 0; nt < 2; ++nt) {
      int ng = sc + wv * 32 + nt * 16 + c;
      unsigned long long pk = 0;
#pragma unroll
      for (int r = 0; r < 4; ++r) {
        int m = q * 4 + r;
        float hn = 0.8f * h32r[nt][r] +
                   0.2f * (xv[nt][r] + acc[nt][0][r] + acc[nt][1][r]);
        hn = fmaxf(hn, 0.f);
        h32r[nt][r] = hn;
        dout[((size_t)t * NB + m0 + m) * NH + ng] = hn;
        union { _Float16 h; unsigned short u; } cv;
        cv.h = (_Float16)hn;
        pk |= (unsigned long long)cv.u << (16 * r);
        if (!last) h_sh[m][ng] = cv.h;   // own-half LDS refresh
        if (last)
          dout[(size_t)NT * NB * NH + (size_t)(m0 + m) * NH + ng] = hn;
      }
      if (!last)
        __hip_atomic_store(
            hbuf64 + ((size_t)slotw * NH + ng) * 32 + (m0 >> 2) + q, pk,
            __ATOMIC_RELAXED, __HIP_MEMORY_SCOPE_AGENT);
    }
    if (last) break;

    __syncthreads();  // (2) drains vmcnt(0): hbuf stores LLC-visible;
                      //     own-half h_sh visible for next step
    if (tid == 0)
      __hip_atomic_store(myflag, t + 1, __ATOMIC_RELAXED,
                         __HIP_MEMORY_SCOPE_AGENT);
  }
}

// ---------------------------------------------------------------------------
extern "C" void kernel_launch(void* const* d_in, const int* in_sizes, int n_in,
                              void* d_out, int out_size, void* d_ws,
                              size_t ws_size, hipStream_t stream) {
  const float* x      = (const float*)d_in[0];   // [512][128][256]
  const float* hidden = (const float*)d_in[1];   // [128][512]
  const float* W_in   = (const float*)d_in[2];   // [512][256]
  const float* W_hh   = (const float*)d_in[3];   // [512][512]
  float* out = (float*)d_out;

  // ws layout (772KB, identical to the passing baseline):
  //   Wf_hh 512KB | Wf_in 256KB (aliased by hbuf after input_proj) | flags 1KB
  _Float16* Wf_hh = (_Float16*)d_ws;
  _Float16* Wf_in = Wf_hh + (size_t)NH * NH;
  unsigned long long* hbuf = (unsigned long long*)Wf_in;  // alias, stream-ordered
  int* flags = (int*)((char*)d_ws + (size_t)NH * NH * 2 + (size_t)NH * NI * 2);

  w_transform<<<196, 256, 0, stream>>>(W_hh, W_in, Wf_hh, Wf_in, flags);
  input_proj<<<(NT * NB) / 16, 256, 0, stream>>>(x, Wf_in, out);

  void* args[] = {(void*)&out, (void*)&hidden, (void*)&Wf_hh, (void*)&hbuf,
                  (void*)&flags};
  hipLaunchCooperativeKernel((void*)recurrence, dim3(16), dim3(512), args, 0,
                             stream);
}

// Round 4
// 1607.550 us; speedup vs baseline: 1.0051x; 1.0051x over previous
//
#include <hip/hip_runtime.h>

typedef _Float16 half8 __attribute__((ext_vector_type(8)));
typedef float f32x4 __attribute__((ext_vector_type(4)));

#define NT 512   // timesteps
#define NB 128   // batch
#define NI 256   // input dim
#define NH 512   // hidden dim
#define FLAG_STRIDE 16  // ints -> 64B per flag, avoid line sharing

// ---------------------------------------------------------------------------
// W (fp32 [N][K]) -> fragment-linear f16 for MFMA B-operand.
// Block b = t_n*KT + t_k; lane l holds 8 elems: n = t_n*16 + (l&15),
// k = t_k*32 + (l>>4)*8 + j. Also zeroes the flags (ws is re-poisoned each
// launch). Grid 196*256 = 50176 >= 32768 + 16384 + 256.
// ---------------------------------------------------------------------------
__global__ void w_transform(const float* __restrict__ Whh,
                            const float* __restrict__ Win,
                            _Float16* __restrict__ Wf_hh,
                            _Float16* __restrict__ Wf_in,
                            int* __restrict__ flags) {
  int tid = blockIdx.x * blockDim.x + threadIdx.x;
  if (tid < 32768) {                    // W_hh: 32 n-tiles * 16 k-tiles
    int l = tid & 63, b = tid >> 6;
    int tk = b & 15, tn = b >> 4;
    int n = tn * 16 + (l & 15);
    int k = tk * 32 + (l >> 4) * 8;
    const float* src = Whh + (size_t)n * NH + k;
    _Float16* dst = Wf_hh + (size_t)tid * 8;
#pragma unroll
    for (int j = 0; j < 8; ++j) dst[j] = (_Float16)src[j];
  } else if (tid < 32768 + 16384) {     // W_in: 32 n-tiles * 8 k-tiles
    int t2 = tid - 32768;
    int l = t2 & 63, b = t2 >> 6;
    int tk = b & 7, tn = b >> 3;
    int n = tn * 16 + (l & 15);
    int k = tk * 32 + (l >> 4) * 8;
    const float* src = Win + (size_t)n * NI + k;
    _Float16* dst = Wf_in + (size_t)t2 * 8;
#pragma unroll
    for (int j = 0; j < 8; ++j) dst[j] = (_Float16)src[j];
  } else if (tid < 32768 + 16384 + 256) {
    flags[tid - 32768 - 16384] = 0;
  }
}

// ---------------------------------------------------------------------------
// Phase 1: xin = x @ W_in^T  (M=65536, K=256, N=512), fp32 out into d_out.
// (unchanged from the passing baseline)
// ---------------------------------------------------------------------------
__global__ __launch_bounds__(256)
void input_proj(const float* __restrict__ x,
                const _Float16* __restrict__ Wf_in,
                float* __restrict__ xin) {
  int lane = threadIdx.x & 63;
  int wv = threadIdx.x >> 6;
  int m0 = blockIdx.x * 16;
  int c = lane & 15, q = lane >> 4;
  int row = m0 + c;

  f32x4 acc[8];
#pragma unroll
  for (int i = 0; i < 8; ++i) acc[i] = (f32x4){0.f, 0.f, 0.f, 0.f};

#pragma unroll
  for (int kc = 0; kc < 8; ++kc) {
    const float4* ap = (const float4*)(x + (size_t)row * NI + kc * 32 + q * 8);
    float4 a0 = ap[0], a1 = ap[1];
    half8 a;
    a[0] = (_Float16)a0.x; a[1] = (_Float16)a0.y;
    a[2] = (_Float16)a0.z; a[3] = (_Float16)a0.w;
    a[4] = (_Float16)a1.x; a[5] = (_Float16)a1.y;
    a[6] = (_Float16)a1.z; a[7] = (_Float16)a1.w;
#pragma unroll
    for (int nt = 0; nt < 8; ++nt) {
      int tn = wv * 8 + nt;
      const half8* bp =
          (const half8*)(Wf_in + (((size_t)(tn * 8 + kc)) * 64 + lane) * 8);
      acc[nt] = __builtin_amdgcn_mfma_f32_16x16x32_f16(a, *bp, acc[nt], 0, 0, 0);
    }
  }
#pragma unroll
  for (int nt = 0; nt < 8; ++nt) {
    int n = wv * 128 + nt * 16 + c;
#pragma unroll
    for (int r = 0; r < 4; ++r) {
      int m = q * 4 + r;
      xin[(size_t)(m0 + m) * NH + n] = acc[nt][r];
    }
  }
}

// ---------------------------------------------------------------------------
// Phase 2: recurrence. 16 wgs = 8 batch-groups x 2 col-slices (256 cols each).
// 512 threads = 8 waves; each wave owns 2 n-tiles (32 cols), all 16 k-chunks
// of W_hh resident in registers (128 regs/lane of B-fragments).
//
// __launch_bounds__(512, 1): round-3's (512,2) capped VGPRs at ~128, which
// forced the 128-reg bfrag array out of registers -> per-step L2 reloads
// serialized against the MFMAs (VGPR_Count=112, +1300 cy/step). Cap 256
// fits bfrag + acc + addressing (~200 regs) with zero spill. Grid is 16
// blocks on 256 CUs, so real occupancy is unchanged.
//
// Protocol = the PROVEN baseline flag scheme, unchanged semantics:
//  * hbuf f16, col-major [2][NH][NB] (aliases Wf_in; never needs zeroing —
//    flags gate every read, and each slot is fully written before its flag).
//  * publisher: epilogue stores h (f16) into slot t&1 via relaxed agent
//    atomics; __syncthreads() (compiler drains vmcnt(0) -> LLC-visible);
//    tid0 stores flag := t+1 (relaxed agent).
//  * consumer at step t: spin partner flag >= t, then load slot (t-1)&1.
//  * slot reuse safe: partner rewrites slot (t-1)&1 only at its step t+1,
//    after observing our flag t+1, stored after our step-t reads completed.
// Latency hiding: own 256 k-cols (our own published half, fresh in LDS) are
// consumed by MFMAs BEFORE the spin, covering the partner's lag + LLC RT.
// Exactly 2 __syncthreads per step, no inline asm, no manual waitcnt.
// ---------------------------------------------------------------------------
__global__ __launch_bounds__(512, 1)
void recurrence(float* __restrict__ dout,          // xin in-place -> h, + final
                const float* __restrict__ h0,
                const _Float16* __restrict__ Wf,   // fragment-linear W_hh
                unsigned long long* __restrict__ hbuf64,  // [2][NH][NB] f16
                int* __restrict__ flags) {
  __shared__ _Float16 h_sh[16][520];   // full h rows (A source), 16B rows

  int g = blockIdx.x >> 1, s = blockIdx.x & 1;
  int tid = threadIdx.x, lane = tid & 63, wv = tid >> 6;  // 8 waves
  int c = lane & 15, q = lane >> 4;
  int m0 = g * 16;            // batch row base
  int sc = s * 256;           // own hidden-col base (also own k-range)
  int P0 = 256 - sc;          // partner col base

  // resident B-fragments: this wave's 2 n-tiles (32 cols), all 16 k-chunks,
  // own-k-first ordering so both MFMA loops use compile-time indices.
  int ntg = s * 16 + wv * 2;
  half8 bfrag[2][16];
#pragma unroll
  for (int nt = 0; nt < 2; ++nt) {
#pragma unroll
    for (int kk = 0; kk < 16; ++kk) {
      int kcg = (kk < 8) ? (s * 8 + kk) : ((8 - s * 8) + (kk - 8));
      bfrag[nt][kk] =
          *(const half8*)(Wf + (((size_t)(ntg + nt) * 16 + kcg) * 64 + lane) * 8);
    }
  }

  // fp32 master state: 2 n-tiles x 4 rows per thread (C-fragment layout)
  float h32r[2][4];
#pragma unroll
  for (int nt = 0; nt < 2; ++nt)
#pragma unroll
    for (int r = 0; r < 4; ++r)
      h32r[nt][r] =
          h0[(size_t)(m0 + q * 4 + r) * NH + sc + wv * 32 + nt * 16 + c];

  // init h_sh (both halves) from h0
  for (int i = tid; i < 16 * 512; i += 512)
    h_sh[i >> 9][i & 511] = (_Float16)h0[(size_t)(m0 + (i >> 9)) * NH + (i & 511)];
  __syncthreads();

  unsigned short* hsb = (unsigned short*)&h_sh[0][0];
  int* fbase = flags + g * 2 * FLAG_STRIDE;
  int* myflag = fbase + s * FLAG_STRIDE;
  int* pflag  = fbase + (1 - s) * FLAG_STRIDE;

#pragma unroll 1
  for (int t = 0; t < NT; ++t) {
    // xin: 8 scattered dwords, consumed in the epilogue (latency hidden)
    const float* xp = dout + ((size_t)t * NB + m0) * NH + sc;
    float xv[2][4];
#pragma unroll
    for (int nt = 0; nt < 2; ++nt)
#pragma unroll
      for (int r = 0; r < 4; ++r)
        xv[nt][r] = xp[(size_t)(q * 4 + r) * NH + wv * 32 + nt * 16 + c];

    // --- own-half MFMAs: k in our own 256 cols (h_sh own half is fresh) ---
    f32x4 acc[2][2];
#pragma unroll
    for (int nt = 0; nt < 2; ++nt) {
      acc[nt][0] = (f32x4){0.f, 0.f, 0.f, 0.f};
      acc[nt][1] = (f32x4){0.f, 0.f, 0.f, 0.f};
    }
#pragma unroll
    for (int kk = 0; kk < 8; ++kk) {
      int kcg = s * 8 + kk;
      half8 a = *(const half8*)&h_sh[c][kcg * 32 + q * 8];
#pragma unroll
      for (int nt = 0; nt < 2; ++nt)
        acc[nt][kk & 1] = __builtin_amdgcn_mfma_f32_16x16x32_f16(
            a, bfrag[nt][kk], acc[nt][kk & 1], 0, 0, 0);
    }

    if (t > 0) {
      // --- spin on partner's publish of step t-1 (value t) ---
      while (__hip_atomic_load(pflag, __ATOMIC_RELAXED,
                               __HIP_MEMORY_SCOPE_AGENT) < t) {
      }
      // --- refill remote half of h_sh: 1024 u64 chunks, 2 per thread ---
      const unsigned long long* pb =
          hbuf64 + ((size_t)((t - 1) & 1) * NH + P0) * 32 + (m0 >> 2);
#pragma unroll
      for (int j = 0; j < 2; ++j) {
        int k = tid + j * 512;          // [0,1024): col=k>>2, row-quad=k&3
        int col = k >> 2, rq = k & 3;
        unsigned long long v = __hip_atomic_load(
            pb + (size_t)col * 32 + rq, __ATOMIC_RELAXED,
            __HIP_MEMORY_SCOPE_AGENT);
#pragma unroll
        for (int i = 0; i < 4; ++i)
          hsb[(size_t)(rq * 4 + i) * 520 + P0 + col] =
              (unsigned short)(v >> (16 * i));
      }
    }
    __syncthreads();  // (1) remote half ready; own-half reads all done

    // --- remote-half MFMAs ---
#pragma unroll
    for (int kk = 8; kk < 16; ++kk) {
      int kcg = (8 - s * 8) + (kk - 8);
      half8 a = *(const half8*)&h_sh[c][kcg * 32 + q * 8];
#pragma unroll
      for (int nt = 0; nt < 2; ++nt)
        acc[nt][kk & 1] = __builtin_amdgcn_mfma_f32_16x16x32_f16(
            a, bfrag[nt][kk], acc[nt][kk & 1], 0, 0, 0);
    }

    // --- epilogue: h_new = relu(0.8 h + 0.2 (xin + P)) ---
    bool last = (t == NT - 1);
    int slotw = t & 1;
#pragma unroll
    for (int nt = 0; nt < 2; ++nt) {
      int ng = sc + wv * 32 + nt * 16 + c;
      unsigned long long pk = 0;
#pragma unroll
      for (int r = 0; r < 4; ++r) {
        int m = q * 4 + r;
        float hn = 0.8f * h32r[nt][r] +
                   0.2f * (xv[nt][r] + acc[nt][0][r] + acc[nt][1][r]);
        hn = fmaxf(hn, 0.f);
        h32r[nt][r] = hn;
        dout[((size_t)t * NB + m0 + m) * NH + ng] = hn;
        union { _Float16 h; unsigned short u; } cv;
        cv.h = (_Float16)hn;
        pk |= (unsigned long long)cv.u << (16 * r);
        if (!last) h_sh[m][ng] = cv.h;   // own-half LDS refresh
        if (last)
          dout[(size_t)NT * NB * NH + (size_t)(m0 + m) * NH + ng] = hn;
      }
      if (!last)
        __hip_atomic_store(
            hbuf64 + ((size_t)slotw * NH + ng) * 32 + (m0 >> 2) + q, pk,
            __ATOMIC_RELAXED, __HIP_MEMORY_SCOPE_AGENT);
    }
    if (last) break;

    __syncthreads();  // (2) drains vmcnt(0): hbuf stores LLC-visible;
                      //     own-half h_sh visible for next step
    if (tid == 0)
      __hip_atomic_store(myflag, t + 1, __ATOMIC_RELAXED,
                         __HIP_MEMORY_SCOPE_AGENT);
  }
}

// ---------------------------------------------------------------------------
extern "C" void kernel_launch(void* const* d_in, const int* in_sizes, int n_in,
                              void* d_out, int out_size, void* d_ws,
                              size_t ws_size, hipStream_t stream) {
  const float* x      = (const float*)d_in[0];   // [512][128][256]
  const float* hidden = (const float*)d_in[1];   // [128][512]
  const float* W_in   = (const float*)d_in[2];   // [512][256]
  const float* W_hh   = (const float*)d_in[3];   // [512][512]
  float* out = (float*)d_out;

  // ws layout (772KB, identical to the passing baseline):
  //   Wf_hh 512KB | Wf_in 256KB (aliased by hbuf after input_proj) | flags 1KB
  _Float16* Wf_hh = (_Float16*)d_ws;
  _Float16* Wf_in = Wf_hh + (size_t)NH * NH;
  unsigned long long* hbuf = (unsigned long long*)Wf_in;  // alias, stream-ordered
  int* flags = (int*)((char*)d_ws + (size_t)NH * NH * 2 + (size_t)NH * NI * 2);

  w_transform<<<196, 256, 0, stream>>>(W_hh, W_in, Wf_hh, Wf_in, flags);
  input_proj<<<(NT * NB) / 16, 256, 0, stream>>>(x, Wf_in, out);

  void* args[] = {(void*)&out, (void*)&hidden, (void*)&Wf_hh, (void*)&hbuf,
                  (void*)&flags};
  hipLaunchCooperativeKernel((void*)recurrence, dim3(16), dim3(512), args, 0,
                             stream);
}